// Round 11
// baseline (90.517 us; speedup 1.0000x reference)
//
#include <hip/hip_runtime.h>

using uint = unsigned int;
typedef unsigned short ushort_t;
typedef float f32x4 __attribute__((ext_vector_type(4)));
typedef short short8 __attribute__((ext_vector_type(8)));

#define B_ 4
#define C_ 256
#define T_ 4096
#define U_ 64

static __device__ __forceinline__ uint f2bf(float f) {
    uint x = __float_as_uint(f);
    return (x + 0x7fffu + ((x >> 16) & 1u)) >> 16;
}

// ---------------------------------------------------------------------------
// Kernel 1: MFMA projections (R10 verbatim). blockIdx.y==0 -> Q from y1;
// ==1 -> K,V from y2. Q,K row-major bf16 [B][T][64]; V transposed Vt[B][64][T].
// ---------------------------------------------------------------------------
__global__ __launch_bounds__(256) void proj_kernel(
    const float* __restrict__ y1, const float* __restrict__ y2,
    const float* __restrict__ Wq, const float* __restrict__ Wk,
    const float* __restrict__ Wv,
    ushort_t* __restrict__ Qb, ushort_t* __restrict__ Kb, ushort_t* __restrict__ Vt)
{
    __shared__ alignas(16) ushort_t wt[2][64][264];

    const int p   = blockIdx.y;
    const int b   = blockIdx.x >> 6;
    const int t0  = (blockIdx.x & 63) << 6;
    const int tid = threadIdx.x;

    {
        const float* W0 = (p == 0) ? Wq : Wk;
#pragma unroll
        for (int k = 0; k < 64; ++k) {
            int idx = tid + 256 * k;
            int c = idx >> 6, u = idx & 63;
            wt[0][u][c] = (ushort_t)f2bf(W0[idx]);
        }
        if (p == 1) {
#pragma unroll
            for (int k = 0; k < 64; ++k) {
                int idx = tid + 256 * k;
                int c = idx >> 6, u = idx & 63;
                wt[1][u][c] = (ushort_t)f2bf(Wv[idx]);
            }
        }
    }
    __syncthreads();

    const int wid = tid >> 6, l = tid & 63;
    const int lm = l & 15, lg = l >> 4;

    const float* ysrc = ((p == 0) ? y1 : y2) + (size_t)b * (C_ * T_);
    const float* yp   = ysrc + (size_t)(8 * lg) * T_ + (t0 + 16 * wid + lm);

    f32x4 acc0[4] = {};
    f32x4 acc1[4] = {};
#pragma unroll
    for (int ks = 0; ks < 8; ++ks) {
        float av[8];
#pragma unroll
        for (int j = 0; j < 8; ++j)
            av[j] = yp[(size_t)(32 * ks + j) * T_];
        short8 af;
#pragma unroll
        for (int j = 0; j < 8; ++j)
            af[j] = (short)f2bf(av[j]);
#pragma unroll
        for (int n = 0; n < 4; ++n) {
            short8 bq = *(const short8*)&wt[0][16 * n + lm][32 * ks + 8 * lg];
            acc0[n] = __builtin_amdgcn_mfma_f32_16x16x32_bf16(af, bq, acc0[n], 0, 0, 0);
            if (p) {
                short8 bv = *(const short8*)&wt[1][16 * n + lm][32 * ks + 8 * lg];
                acc1[n] = __builtin_amdgcn_mfma_f32_16x16x32_bf16(af, bv, acc1[n], 0, 0, 0);
            }
        }
    }

    ushort_t* O0 = p ? Kb : Qb;
#pragma unroll
    for (int n = 0; n < 4; ++n)
#pragma unroll
        for (int r = 0; r < 4; ++r) {
            int t = t0 + 16 * wid + 4 * lg + r;
            int u = 16 * n + lm;
            O0[((size_t)b * T_ + t) * U_ + u] = (ushort_t)f2bf(acc0[n][r]);
            if (p)
                Vt[((size_t)b * U_ + u) * T_ + t] = (ushort_t)f2bf(acc1[n][r]);
        }
}

// ---------------------------------------------------------------------------
// Kernel 2: MFMA banded attention, high-occupancy. 1024 blocks x 256 thr
// (4 waves, 16 rows/block). No K/Q/V LDS staging (direct coalesced global,
// L2/L3-hot). LDS = P only (~9.8 KB) -> 8 blocks/CU. V^T A-frags hoisted
// into regs before the last barrier -> NO vmcnt waits after the store burst.
// All a/out stores are PLAIN stores (fill-kernel pattern).
// ---------------------------------------------------------------------------
__global__ __launch_bounds__(256, 8) void attn_kernel(
    const ushort_t* __restrict__ Qb, const ushort_t* __restrict__ Kb,
    const ushort_t* __restrict__ Vt, float* __restrict__ gout)
{
    __shared__ alignas(16) ushort_t alds[16][296];   // P bf16, 9.25 KB
    __shared__ float sums[4][20];                    // softmax partials

    const int bid = blockIdx.x;
    const int b   = bid >> 8;
    const int i0  = (bid & 255) << 4;
    const int tid = threadIdx.x;
    const int w   = tid >> 6, l = tid & 63;
    const int lm  = l & 15, lg = l >> 4;

    const int jb2    = max(0, i0 - 127) & ~7;        // 8-aligned window start
    const int jend   = min(T_, i0 + 144);
    const int width2 = jend - jb2;                   // mult of 16, <= 272
    const int NT     = width2 >> 4;                  // j-tiles, <= 17

    // ---- hoisted register loads (all retire at barrier B, not after) ----
    const ushort_t* qrow = Qb + ((size_t)b * T_ + i0 + lm) * U_ + 8 * lg;
    const short8 aq0 = *(const short8*)(qrow);
    const short8 aq1 = *(const short8*)(qrow + 32);

    short8 pa[9];
    {
        const ushort_t* vrow = Vt + ((size_t)(b * U_ + 16 * w + lm)) * T_;
#pragma unroll
        for (int kc = 0; kc < 9; ++kc) {
            int jcol = min(jb2 + 32 * kc + 8 * lg, T_ - 8);
            pa[kc] = *(const short8*)(vrow + jcol);
        }
    }

    // ---- zero P ----
    {
        short8 z = {};
        short8* af = (short8*)&alds[0][0];
#pragma unroll
        for (int k = 0; k < 3; ++k) {
            int idx = tid + 256 * k;
            if (idx < 592) af[idx] = z;
        }
    }

    // ---- S phase: Q x K^T via MFMA (K direct from global), exp, partials --
    f32x4 ev[5];
    f32x4 psum = {};
#pragma unroll
    for (int s = 0; s < 5; ++s) ev[s] = (f32x4)(0.f);
#pragma unroll
    for (int s = 0; s < 5; ++s) {
        const int jt = 4 * s + w;                    // wave-uniform
        if (jt < NT) {
            const int j = jb2 + 16 * jt + lm;
            const ushort_t* kp = Kb + ((size_t)b * T_ + j) * U_ + 8 * lg;
            short8 bk0 = *(const short8*)(kp);
            short8 bk1 = *(const short8*)(kp + 32);
            f32x4 acc = {};
            acc = __builtin_amdgcn_mfma_f32_16x16x32_bf16(aq0, bk0, acc, 0, 0, 0);
            acc = __builtin_amdgcn_mfma_f32_16x16x32_bf16(aq1, bk1, acc, 0, 0, 0);
#pragma unroll
            for (int r = 0; r < 4; ++r) {
                int i = i0 + 4 * lg + r;
                bool val = (j >= i - 127) && (j <= i + 128);
                float e = val ? __expf(acc[r] * 0.125f) : 0.f;
                ev[s][r] = e;
                psum[r] += e;
            }
        }
    }
#pragma unroll
    for (int m = 1; m < 16; m <<= 1) {
#pragma unroll
        for (int r = 0; r < 4; ++r)
            psum[r] += __shfl_xor(psum[r], m, 64);
    }
    if (lm == 0)
        *(f32x4*)&sums[w][4 * lg] = psum;
    __syncthreads();                                  // barrier A

    // ---- totals + normalize + stage P ----
    f32x4 rtot = *(const f32x4*)&sums[0][4 * lg];
    rtot += *(const f32x4*)&sums[1][4 * lg];
    rtot += *(const f32x4*)&sums[2][4 * lg];
    rtot += *(const f32x4*)&sums[3][4 * lg];
    f32x4 rinv;
#pragma unroll
    for (int r = 0; r < 4; ++r)
        rinv[r] = __builtin_amdgcn_rcpf(rtot[r]);

#pragma unroll
    for (int s = 0; s < 5; ++s) {
        const int jt = 4 * s + w;
        if (jt < NT) {
#pragma unroll
            for (int r = 0; r < 4; ++r) {
                float a = ev[s][r] * rinv[r];
                ev[s][r] = a;
                alds[4 * lg + r][16 * jt + lm] = (ushort_t)f2bf(a);
            }
        }
    }
    __syncthreads();                                  // barrier B (drains pa/aq)

    float* aout = gout + (size_t)B_ * U_ * T_;

    // ---- band stores (plain; nothing after this waits on vmcnt) ----
#pragma unroll
    for (int s = 0; s < 5; ++s) {
        const int jt = 4 * s + w;
        if (jt < NT) {
            const int j = jb2 + 16 * jt + lm;
#pragma unroll
            for (int r = 0; r < 4; ++r) {
                int i = i0 + 4 * lg + r;
                if ((j >= i - 127) && (j <= i + 128))
                    aout[((size_t)b * T_ + i) * T_ + j] = ev[s][r];
            }
        }
    }
    // ---- zero stores: out-of-band of this wave's 4 rows (plain) ----
    {
        const f32x4 zz = (f32x4)(0.f);
#pragma unroll
        for (int rr = 0; rr < 4; ++rr) {
            const int i   = i0 + 4 * w + rr;
            const int jlo = max(0, i - 127);
            const int jhi = min(T_ - 1, i + 128);
            float* rowp = aout + ((size_t)b * T_ + i) * T_;
            f32x4* row4 = (f32x4*)rowp;
            int nleft4 = jlo >> 2;
            for (int k = l; k < nleft4; k += 64)
                row4[k] = zz;
            int rem = jlo & 3;
            if (l < rem)
                rowp[(jlo & ~3) + l] = 0.f;
            int js = jhi + 1;
            int ah = (4 - (js & 3)) & 3;
            if (l < ah && js + l < T_)
                rowp[js + l] = 0.f;
            int js4 = (js + ah) >> 2;
            for (int k = js4 + l; k < T_ / 4; k += 64)
                row4[k] = zz;
        }
    }

    // ---- PV via MFMA: A = V^T (regs), B = P (LDS) -> coalesced out ----
    {
        f32x4 pacc = {};
#pragma unroll
        for (int kc = 0; kc < 9; ++kc) {
            short8 pb = *(const short8*)&alds[lm][32 * kc + 8 * lg];
            pacc = __builtin_amdgcn_mfma_f32_16x16x32_bf16(pa[kc], pb, pacc, 0, 0, 0);
        }
#pragma unroll
        for (int r = 0; r < 4; ++r)
            gout[((size_t)(b * U_ + 16 * w + 4 * lg + r)) * T_ + i0 + lm] = pacc[r];
    }
}

// ---------------------------------------------------------------------------
extern "C" void kernel_launch(void* const* d_in, const int* in_sizes, int n_in,
                              void* d_out, int out_size, void* d_ws, size_t ws_size,
                              hipStream_t stream)
{
    const float* y1 = (const float*)d_in[0];
    const float* y2 = (const float*)d_in[1];
    const float* Wq = (const float*)d_in[2];
    const float* Wk = (const float*)d_in[3];
    const float* Wv = (const float*)d_in[4];
    // d_in[5] = attention_width (== 256, compiled in)

    // workspace: Qb, Kb [B][T][64] bf16; Vt [B][64][T] bf16
    ushort_t* Qb = (ushort_t*)d_ws;
    ushort_t* Kb = Qb + (size_t)B_ * T_ * U_;
    ushort_t* Vt = Kb + (size_t)B_ * T_ * U_;

    float* gout = (float*)d_out;

    proj_kernel<<<dim3(B_ * (T_ / 64), 2), 256, 0, stream>>>(y1, y2, Wq, Wk, Wv, Qb, Kb, Vt);
    attn_kernel<<<1024, 256, 0, stream>>>(Qb, Kb, Vt, gout);
}